// Round 15
// baseline (2854.738 us; speedup 1.0000x reference)
//
#include <hip/hip_runtime.h>

#define TST   1024
#define OWN   16           // own tile: 16x16
#define HALO  8            // 8 rings -> 8 stages -> 2 RK4 steps per exchange
#define TDIM  32           // 32x32 tile = own 16x16 + 8-halo
#define NT    1024         // 16 waves; wave w owns tile rows {2w, 2w+1}
#define NW    16
#define NB    256          // 16x16 blocks, one per CU

typedef float v4f __attribute__((ext_vector_type(4)));
typedef unsigned u32x2 __attribute__((ext_vector_type(2)));

#define AG __HIP_MEMORY_SCOPE_AGENT
__device__ __forceinline__ float agload (const float* p){ return __hip_atomic_load (p, __ATOMIC_RELAXED, AG); }
__device__ __forceinline__ int   agloadi(const int* p)  { return __hip_atomic_load (p, __ATOMIC_RELAXED, AG); }
__device__ __forceinline__ void  agstoref(float* p,float v){      __hip_atomic_store(p, v, __ATOMIC_RELAXED, AG); }
__device__ __forceinline__ void  agstorei(int* p,int v) {         __hip_atomic_store(p, v, __ATOMIC_RELAXED, AG); }

// Device-scope (sc1) 16B accesses, coherent at Infinity Cache. Stamp rides in
// .w -> each halo cell self-validates. Load+waitcnt in ONE asm block.
__device__ __forceinline__ v4f ld16_dev(const v4f* p) {
    v4f r;
    asm volatile("global_load_dwordx4 %0, %1, off sc1\n\ts_waitcnt vmcnt(0)"
                 : "=v"(r) : "v"(p) : "memory");
    return r;
}
__device__ __forceinline__ void st16_dev(v4f* p, v4f v) {
    asm volatile("global_store_dwordx4 %0, %1, off sc1" :: "v"(p), "v"(v) : "memory");
}

// In-wave vertical exchange: v_permlane32_swap_b32 swaps lanes 0-31 of vdst
// with lanes 32-63 of vsrc. With vdst=vsrc=v: result.x lanes0-31 = v[lane+32],
// result.y lanes32-63 = v[lane-32] -> partner = lowHalf ? r.x : r.y.
// Full-exec call site (wave-uniform guard only) -> no fetch-inactive needed.
__device__ __forceinline__ float swap_half(float v, bool lowHalf) {
    u32x2 r = __builtin_amdgcn_permlane32_swap(
        __float_as_uint(v), __float_as_uint(v), false, false);
    return __uint_as_float(lowHalf ? r.x : r.y);
}

__global__ void __launch_bounds__(NT)
mm_solver(const float* __restrict__ signal,
          const float* __restrict__ B_ext,
          const float* __restrict__ Msat,
          const float* __restrict__ src_mask,
          const float* __restrict__ probe_mask,
          float* __restrict__ out,
          float* __restrict__ ws)
{
    const int b  = (int)blockIdx.x;
    const int bx = b & 15, by = b >> 4;
    const int t  = (int)threadIdx.x;
    const int tr = t >> 5, tc = t & 31;      // 32-wide rows, rank == t
    const int wv = t >> 6;                   // wave id 0..15

    const int grow = by * OWN - HALO + tr;
    const int gcol = bx * OWN - HALO + tc;
    const bool inG = (grow >= 0 && grow < 256 && gcol >= 0 && gcol < 256);
    const bool own = (tr >= HALO && tr < HALO + OWN && tc >= HALO && tc < HALO + OWN);

    // Cone predication (R11, verified): participate in the phase-q write iff
    // dOwn <= 8-q; read phase-(q-1) data iff dOwn <= 8-q (same predicate).
    const int dyO = (tr < HALO) ? (HALO - tr) : ((tr > 23) ? (tr - 23) : 0);
    const int dxO = (tc < HALO) ? (HALO - tc) : ((tc > 23) ? (tc - 23) : 0);
    const int dOwn = dxO + dyO;
    // Wave row-distance (wave = rows {2w,2w+1}): min dy over its rows.
    const int dyW = (wv < 4) ? (7 - 2 * wv) : ((wv >= 12) ? (2 * wv - 23) : 0);

    // R14/R15: IN-WAVE VERTICAL NEIGHBOR VIA permlane32_swap. A wave's two
    // rows are vertical neighbors of each other (lane^32). Parity proof: grow
    // parity == tr parity, so the physical clamp rows (grow==255 for even-tr
    // up, grow==0 for odd-tr down) are UNREACHABLE, and the in-wave row is
    // never a tile edge -> the swapped value needs NO clamp select. The
    // stencil consumes u+d (symmetric sum): vin+vlds == u+d bitwise by
    // commutativity, no which-is-which select. Freshness: at VSWAP time
    // (just after PSYNC, before any e update this phase) every lane's e holds
    // its phase-(q-1) exposure; a consumer active at q has dOwn<=8-q, its
    // vertical neighbor dOwn'<=9-q was active at q-1 -> swapped value is
    // exactly u (or d). STAGE DS ops 5 -> 4 (-20% of the dominant DS-pipe
    // term); +12 VALU/phase (pipe at 49%). Unlike R6: no clamp cndmasks on
    // data, no serial-chain select web.

    // ws: pub v4f[2][65536] (2MB) | priv float[NB][TST] (1MB) | doneA int[NB]
    v4f*   pub   = (v4f*)ws;
    float* priv  = ws + 2 * 65536 * 4;
    int*   doneA = (int*)(priv + NB * TST);
    const int pubStride = 65536;

    __shared__ v4f  EB[2][TDIM * TDIM];      // 32 KB exposure buffers
    __shared__ float sigS[TST];
    __shared__ int   hasP;
    __shared__ int   pfl[NB];
    __shared__ float redS[NW];
    __shared__ float pmsS;

    // Phase sync = ONE hardware s_barrier per stage (8/group), 16 waves.
    // Double-buffer hazard proof unchanged from R7/R11 (verified). PSYNC is
    // OUTSIDE all predicates -> every wave executes all 8 barriers/group.
#define PSYNC() do { \
    asm volatile("s_waitcnt lgkmcnt(0)" ::: "memory"); \
    __builtin_amdgcn_s_barrier(); \
    asm volatile("" ::: "memory"); \
} while (0)

    const bool lane0 = ((t & 63) == 0);
    const bool lowHalf = ((tr & 1) == 0);    // lane < 32 <=> even tile row

    // constants (identical fp expressions to the bitwise-validated kernels)
    const float invd   = (float)(1.0 / (double)((float)(50e-9 * 50e-9)));
    const float h      = (float)(1.7595e11 * 5e-12);
    const float hh     = (float)(0.5 * (1.7595e11 * 5e-12));
    const float h6     = (float)((1.7595e11 * 5e-12) / 6.0);
    const float alpha  = 0.01f;
    const float inv1a2 = (float)(1.0 / (1.0 + 0.01 * 0.01));

    const int growc = grow < 0 ? 0 : (grow > 255 ? 255 : grow);
    const int gcolc = gcol < 0 ? 0 : (gcol > 255 ? 255 : gcol);
    const int idxg  = growc * 256 + gcolc;
    const float bxv = B_ext[idxg], byv = B_ext[65536 + idxg], bzv = B_ext[131072 + idxg];
    const float ms  = Msat[idxg];
    const float sxv = src_mask[idxg], syv = src_mask[65536 + idxg], szv = src_mask[131072 + idxg];
    const float pm  = probe_mask[idxg];
    const float ce   = 7.3e-12f / ms;
    const float cdem = -(float)(4.0e-7 * 3.14159265358979323846) * ms;

    // Neighbor offsets. Cross-wave vertical per lane: even tr needs DOWN
    // (row tr-1, other wave), odd tr needs UP (row tr+1, other wave); clamps
    // (tile edge + physical Neumann) exactly as R11's offU/offD.
    const int idx  = t;
    const int offU = ((tr < TDIM - 1) && (grow < 255)) ?  TDIM : 0;
    const int offD = ((tr > 0)        && (grow > 0))   ? -TDIM : 0;
    const int offV = lowHalf ? offD : offU;  // the LDS-side vertical neighbor
    const int offR = ((tc < TDIM - 1) && (gcol < 255)) ?  1 : 0;
    const int offL = ((tc > 0)        && (gcol > 0))   ? -1 : 0;

    const int slotOff = idxg;                 // poll slot (own: == publish slot)

    // relax() is bitwise identity; m0 = z-hat exactly. Group 0 needs no halo
    // poll; owners pre-stamp parity-1 with -1 so no garbage stamp validates.
    float mx = 0.0f, my = 0.0f, mz = 1.0f;

    if (own) {
        st16_dev(pub + slotOff,             (v4f){0.0f, 0.0f, 1.0f, __int_as_float(0)});
        st16_dev(pub + pubStride + slotOff, (v4f){0.0f, 0.0f, 1.0f, __int_as_float(-1)});
    }
    for (int k = t; k < TST; k += NT) sigS[k] = signal[k];
    if (t == 40) hasP = 0;
    __syncthreads();
    const bool pcell = own && (pm != 0.0f);
    if (pcell) atomicOr(&hasP, 1);
    const bool waveP = (__ballot(pcell) != 0ull);   // wave-uniform
    __syncthreads();
    const int hasPr = hasP;
    if (hasPr) for (int k = t; k < TST; k += NT) agstoref(&priv[b * TST + k], 0.0f);
    __syncthreads();   // drain zero-stores before step-0 probe atomics

    const bool haloT = inG && !own && (dOwn <= HALO);
    // e initialized (= m) so never-active lanes feed defined bits to swaps.
    float ex = 0.0f, ey = 0.0f, ez = 1.0f;
    float ax, ay, az, kx, ky, kz, btx, bty, btz;
    float vinX, vinY, vinZ;

#define VSWAP() do { \
    vinX = swap_half(ex, lowHalf); \
    vinY = swap_half(ey, lowHalf); \
    vinZ = swap_half(ez, lowHalf); \
} while (0)

// Stencil: vertical pair = {in-wave via swap (vin), cross-wave via LDS (vv)};
// vin+vv.x == u+d bitwise (commutative). l/r unchanged from R11.
#define STAGEV(SB) do { \
    const v4f vv = EB[SB][idx + offV]; \
    const v4f r = EB[SB][idx + offR]; \
    const v4f l = EB[SB][idx + offL]; \
    float lx = ((vinX + vv.x - 2.0f * ex) + (r.x + l.x - 2.0f * ex)) * invd; \
    float ly = ((vinY + vv.y - 2.0f * ey) + (r.y + l.y - 2.0f * ey)) * invd; \
    float lz = ((vinZ + vv.z - 2.0f * ez) + (r.z + l.z - 2.0f * ez)) * invd; \
    float Bx = btx + ce * lx; \
    float By = bty + ce * ly; \
    float Bz = btz + ce * lz + cdem * ez; \
    float cx = ey * Bz - ez * By; \
    float cy = ez * Bx - ex * Bz; \
    float cz = ex * By - ey * Bx; \
    float dx = ey * cz - ez * cy; \
    float dy = ez * cx - ex * cz; \
    float dz = ex * cy - ey * cx; \
    kx = -(cx + alpha * dx) * inv1a2; \
    ky = -(cy + alpha * dy) * inv1a2; \
    kz = -(cz + alpha * dz) * inv1a2; \
} while (0)

#define WRE(DB) do { EB[DB][idx] = (v4f){ex, ey, ez, 0.0f}; } while (0)

// One full RK4 step with cone predication (R11 structure). Wave-uniform dyW
// guard wraps {VSWAP + per-lane work} per sub-phase; barriers stay outside.
#define RK4_STEP(S, A) do { \
    if (dOwn <= (A)) { \
        btx = bxv + (S) * sxv;  bty = byv + (S) * syv;  btz = bzv + (S) * szv; \
        ex = mx; ey = my; ez = mz; \
        WRE(0); \
    } \
    PSYNC(); \
    if (dyW <= (A) - 1) { VSWAP(); \
    if (dOwn <= (A) - 1) { \
        STAGEV(0);                         /* k1 */ \
        ax = kx; ay = ky; az = kz; \
        ex = mx + hh * kx; ey = my + hh * ky; ez = mz + hh * kz; \
        WRE(1); \
    } } \
    PSYNC(); \
    if (dyW <= (A) - 2) { VSWAP(); \
    if (dOwn <= (A) - 2) { \
        STAGEV(1);                         /* k2 */ \
        ax += 2.0f * kx; ay += 2.0f * ky; az += 2.0f * kz; \
        ex = mx + hh * kx; ey = my + hh * ky; ez = mz + hh * kz; \
        WRE(0); \
    } } \
    PSYNC(); \
    if (dyW <= (A) - 3) { VSWAP(); \
    if (dOwn <= (A) - 3) { \
        STAGEV(0);                         /* k3 */ \
        ax += 2.0f * kx; ay += 2.0f * ky; az += 2.0f * kz; \
        ex = mx + h * kx; ey = my + h * ky; ez = mz + h * kz; \
        WRE(1); \
    } } \
    PSYNC(); \
    if (dyW <= (A) - 4) { VSWAP(); \
    if (dOwn <= (A) - 4) { \
        STAGEV(1);                         /* k4 */ \
        ax += kx; ay += ky; az += kz; \
        mx += h6 * ax; my += h6 * ay; mz += h6 * az; \
    } } \
} while (0)

#define PROBE(I_) do { \
    if (waveP) { \
        float c = pcell ? mx * ms * pm : 0.0f; \
        _Pragma("unroll") \
        for (int off = 32; off > 0; off >>= 1) c += __shfl_down(c, off, 64); \
        if (lane0) atomicAdd(&priv[b * TST + (I_)], c); \
    } \
} while (0)

    for (int i = 0; i < TST; i += 2) {
        const int I = i >> 1;                 // 2-step group index

        // Halo refresh ONCE per group: poll my cell's stamped slot (parity
        // I&1) until stamp>=I. Skipped at I==0 (m_0 analytic). Miss ->
        // s_sleep(1) backoff. Cross-block chain strictly decreases group
        // index -> no premature overwrite, no deadlock (proof as R5-R11).
        if (haloT && I) {
            const v4f* p = pub + (I & 1) * pubStride + slotOff;
            for (;;) {
                v4f hv = ld16_dev(p);
                if (__float_as_int(hv.w) >= I) { mx = hv.x; my = hv.y; mz = hv.z; break; }
                __builtin_amdgcn_s_sleep(1);
            }
        }

        RK4_STEP(sigS[i],     8);             // step A -> m_{i+1}
        PROBE(i);
        RK4_STEP(sigS[i + 1], 4);             // step B -> m_{i+2}
        PROBE(i + 1);

        // publish m_{i+2}, stamp I+1, parity (I+1)&1 (fire-and-forget, global)
        if (own) st16_dev(pub + ((I + 1) & 1) * pubStride + slotOff,
                          (v4f){mx, my, mz, __int_as_float(I + 1)});
    }

    // ---- finalize ----
    __syncthreads();   // TRUE barrier: drains vmcnt -> publishes/atomics done
    if (t == 0) agstorei(&doneA[b], 0x5D0000 | hasPr);

    if (b == 0) {
        if (t < NB) {
            int v;
            for (;;) { v = agloadi(&doneA[t]); if ((v & ~1) == 0x5D0000) break;
                       __builtin_amdgcn_s_sleep(8); }
            pfl[t] = v & 1;
        }
        __syncthreads();
        float ps = 0.0f;
        for (int k = t; k < 65536; k += NT) ps += probe_mask[k];
        #pragma unroll
        for (int off = 32; off > 0; off >>= 1) ps += __shfl_down(ps, off, 64);
        if (lane0) redS[wv] = ps;
        __syncthreads();
        if (t == 0) { float q = 0.0f; for (int w = 0; w < NW; ++w) q += redS[w]; pmsS = q; }
        __syncthreads();
        const float pms = pmsS;
        for (int o = t; o < TST; o += NT) {
            float sm = 0.0f;
            for (int j = 0; j < NB; ++j) if (pfl[j]) sm += agload(&priv[j * TST + o]);
            out[o] = sm / pms;
        }
    }
}

extern "C" void kernel_launch(void* const* d_in, const int* in_sizes, int n_in,
                              void* d_out, int out_size, void* d_ws, size_t ws_size,
                              hipStream_t stream)
{
    const float* signal = (const float*)d_in[0];
    const float* B_ext  = (const float*)d_in[1];
    const float* Msat   = (const float*)d_in[2];
    const float* src    = (const float*)d_in[3];
    const float* probe  = (const float*)d_in[4];
    float* out = (float*)d_out;
    float* ws  = (float*)d_ws;

    void* args[] = { &signal, &B_ext, &Msat, &src, &probe, &out, &ws };
    (void)in_sizes; (void)n_in; (void)out_size; (void)ws_size;

    // 256 blocks (16x16 own tiles, 8-deep halo) x 1024 threads, 1 cell/thread.
    // R15 = R11 champion (barrier phases + cone predication) + in-wave
    // vertical neighbor via v_permlane32_swap_b32: STAGE DS ops 5->4, the
    // swapped path is clamp-free by row-parity, and u+d symmetry keeps the
    // arithmetic bitwise identical. Cross-block exchange every 2 RK4 steps
    // via stamped IF$ slots.
    hipLaunchCooperativeKernel(reinterpret_cast<void*>(mm_solver),
                               dim3(NB), dim3(NT), args, 0, stream);
}

// Round 16
// 2642.638 us; speedup vs baseline: 1.0803x; 1.0803x over previous
//
#include <hip/hip_runtime.h>

#define TST   1024
#define OWN   16           // own tile: 16x16
#define HALO  8            // 8 rings -> 8 stages -> 2 RK4 steps per exchange
#define TDIM  32           // 32x32 tile = own 16x16 + 8-halo
#define NT    1024         // 16 waves; wave w owns tile rows {2w, 2w+1}
#define NW    16
#define NB    256          // 16x16 blocks, one per CU

typedef float v4f __attribute__((ext_vector_type(4)));

#define AG __HIP_MEMORY_SCOPE_AGENT
__device__ __forceinline__ float agload (const float* p){ return __hip_atomic_load (p, __ATOMIC_RELAXED, AG); }
__device__ __forceinline__ int   agloadi(const int* p)  { return __hip_atomic_load (p, __ATOMIC_RELAXED, AG); }
__device__ __forceinline__ void  agstoref(float* p,float v){      __hip_atomic_store(p, v, __ATOMIC_RELAXED, AG); }
__device__ __forceinline__ void  agstorei(int* p,int v) {         __hip_atomic_store(p, v, __ATOMIC_RELAXED, AG); }

// Device-scope (sc1) 16B accesses, coherent at Infinity Cache. Stamp rides in
// .w -> each halo cell self-validates. Load+waitcnt in ONE asm block.
__device__ __forceinline__ v4f ld16_dev(const v4f* p) {
    v4f r;
    asm volatile("global_load_dwordx4 %0, %1, off sc1\n\ts_waitcnt vmcnt(0)"
                 : "=v"(r) : "v"(p) : "memory");
    return r;
}
__device__ __forceinline__ void st16_dev(v4f* p, v4f v) {
    asm volatile("global_store_dwordx4 %0, %1, off sc1" :: "v"(p), "v"(v) : "memory");
}

__global__ void __launch_bounds__(NT)
mm_solver(const float* __restrict__ signal,
          const float* __restrict__ B_ext,
          const float* __restrict__ Msat,
          const float* __restrict__ src_mask,
          const float* __restrict__ probe_mask,
          float* __restrict__ out,
          float* __restrict__ ws)
{
    const int b  = (int)blockIdx.x;
    const int bx = b & 15, by = b >> 4;
    const int t  = (int)threadIdx.x;
    const int tr = t >> 5, tc = t & 31;      // 32-wide rows, rank == t
    const int wv = t >> 6;                   // wave id 0..15

    const int grow = by * OWN - HALO + tr;
    const int gcol = bx * OWN - HALO + tc;
    const bool inG = (grow >= 0 && grow < 256 && gcol >= 0 && gcol < 256);
    const bool own = (tr >= HALO && tr < HALO + OWN && tc >= HALO && tc < HALO + OWN);

    // CONE PREDICATION (champion R11): dOwn = L1 distance from this cell to
    // the own 16x16 region in tile coords. A cell's stage-s value influences
    // own cells (by stage 8) iff dOwn <= 8-s. So: write exposure phase p iff
    // dOwn <= 8-p; compute stage s iff dOwn <= 8-s. Cell-phase work 8192 ->
    // ~4200 per group; row-halo waves go FULLY idle progressively. Tile-edge
    // cells never compute a stencil, so tile-edge garbage is never generated;
    // every consumed value is exact (consumer at stage s has d<=8-s; its
    // neighbors have d<=9-s and wrote phase s-1 under the d<=8-(s-1) rule).
    // Cells with d>8 do nothing at all (nothing reads them).
    const int dyO = (tr < HALO) ? (HALO - tr) : ((tr > 23) ? (tr - 23) : 0);
    const int dxO = (tc < HALO) ? (HALO - tc) : ((tc > 23) ? (tc - 23) : 0);
    const int dOwn = dxO + dyO;

    // ws: pub v4f[2][65536] (2MB) | priv float[NB][TST] (1MB) | doneA int[NB]
    v4f*   pub   = (v4f*)ws;
    float* priv  = ws + 2 * 65536 * 4;
    int*   doneA = (int*)(priv + NB * TST);
    const int pubStride = 65536;

    __shared__ v4f  EB[2][TDIM * TDIM];      // 32 KB exposure buffers
    __shared__ float sigS[TST];
    __shared__ int   hasP;
    __shared__ int   pfl[NB];
    __shared__ float redS[NW];
    __shared__ float pmsS;

    // Phase sync = ONE hardware s_barrier per stage (8/group), 16 waves.
    // Double-buffer hazard proof (verified R7/R11): phase p writes EB[p&1] ->
    // lgkmcnt(0)+barrier -> reads EB[p&1]; the overwrite of EB[(p+1)&1]
    // (read at phase p-1) is separated from those reads by the phase-p
    // barrier (reads drained by the waitcnt preceding it). PSYNC is OUTSIDE
    // all predicates -> every wave executes all 8 barriers/group.
#define PSYNC() do { \
    asm volatile("s_waitcnt lgkmcnt(0)" ::: "memory"); \
    __builtin_amdgcn_s_barrier(); \
    asm volatile("" ::: "memory"); \
} while (0)

    const bool lane0 = ((t & 63) == 0);

    // constants (identical fp expressions to the bitwise-validated kernels)
    const float invd   = (float)(1.0 / (double)((float)(50e-9 * 50e-9)));
    const float h      = (float)(1.7595e11 * 5e-12);
    const float hh     = (float)(0.5 * (1.7595e11 * 5e-12));
    const float h6     = (float)((1.7595e11 * 5e-12) / 6.0);
    const float alpha  = 0.01f;
    const float inv1a2 = (float)(1.0 / (1.0 + 0.01 * 0.01));

    const int growc = grow < 0 ? 0 : (grow > 255 ? 255 : grow);
    const int gcolc = gcol < 0 ? 0 : (gcol > 255 ? 255 : gcol);
    const int idxg  = growc * 256 + gcolc;
    const float bxv = B_ext[idxg], byv = B_ext[65536 + idxg], bzv = B_ext[131072 + idxg];
    const float ms  = Msat[idxg];
    const float sxv = src_mask[idxg], syv = src_mask[65536 + idxg], szv = src_mask[131072 + idxg];
    const float pm  = probe_mask[idxg];
    const float ce   = 7.3e-12f / ms;
    const float cdem = -(float)(4.0e-7 * 3.14159265358979323846) * ms;

    // Neighbor offsets: physical Neumann clamp (exact) + tile-edge clamp.
    // With predication the tile-edge clamp is never exercised by an active
    // stencil at a stage where it could matter; kept verbatim for bitwise
    // identity. Row-uniform.
    const int idx  = t;
    const int offU = ((tr < TDIM - 1) && (grow < 255)) ?  TDIM : 0;
    const int offD = ((tr > 0)        && (grow > 0))   ? -TDIM : 0;
    const int offR = ((tc < TDIM - 1) && (gcol < 255)) ?  1 : 0;
    const int offL = ((tc > 0)        && (gcol > 0))   ? -1 : 0;

    const int slotOff = idxg;                 // poll slot (own: == publish slot)

    // relax() is bitwise identity; m0 = z-hat exactly. Group 0 needs no halo
    // poll; owners pre-stamp parity-1 with -1 so no garbage stamp validates.
    float mx = 0.0f, my = 0.0f, mz = 1.0f;

    if (own) {
        st16_dev(pub + slotOff,             (v4f){0.0f, 0.0f, 1.0f, __int_as_float(0)});
        st16_dev(pub + pubStride + slotOff, (v4f){0.0f, 0.0f, 1.0f, __int_as_float(-1)});
    }
    for (int k = t; k < TST; k += NT) sigS[k] = signal[k];
    if (t == 40) hasP = 0;
    __syncthreads();
    const bool pcell = own && (pm != 0.0f);
    if (pcell) atomicOr(&hasP, 1);
    const bool waveP = (__ballot(pcell) != 0ull);   // wave-uniform
    __syncthreads();
    const int hasPr = hasP;
    if (hasPr) for (int k = t; k < TST; k += NT) agstoref(&priv[b * TST + k], 0.0f);
    __syncthreads();   // drain zero-stores before step-0 probe atomics

    // Poll only cells that participate (dOwn <= 8); d>8 corners never write.
    const bool haloT = inG && !own && (dOwn <= HALO);
    float ex, ey, ez, ax, ay, az, kx, ky, kz, btx, bty, btz;

#define STAGE(SB) do { \
    const v4f u = EB[SB][idx + offU]; \
    const v4f d = EB[SB][idx + offD]; \
    const v4f r = EB[SB][idx + offR]; \
    const v4f l = EB[SB][idx + offL]; \
    float lx = ((u.x + d.x - 2.0f * ex) + (r.x + l.x - 2.0f * ex)) * invd; \
    float ly = ((u.y + d.y - 2.0f * ey) + (r.y + l.y - 2.0f * ey)) * invd; \
    float lz = ((u.z + d.z - 2.0f * ez) + (r.z + l.z - 2.0f * ez)) * invd; \
    float Bx = btx + ce * lx; \
    float By = bty + ce * ly; \
    float Bz = btz + ce * lz + cdem * ez; \
    float cx = ey * Bz - ez * By; \
    float cy = ez * Bx - ex * Bz; \
    float cz = ex * By - ey * Bx; \
    float dx = ey * cz - ez * cy; \
    float dy = ez * cx - ex * cz; \
    float dz = ex * cy - ey * cx; \
    kx = -(cx + alpha * dx) * inv1a2; \
    ky = -(cy + alpha * dy) * inv1a2; \
    kz = -(cz + alpha * dz) * inv1a2; \
} while (0)

#define WRE(DB) do { EB[DB][idx] = (v4f){ex, ey, ez, 0.0f}; } while (0)

// One full RK4 step with cone predication. A = phase budget at step entry
// (8 for step A of a group, 4 for step B). Op order between barriers is
// EXACTLY R7's: [WRE] B [STAGE..WRE] B [STAGE..WRE] B [STAGE..WRE] B [STAGE..]
#define RK4_STEP(S, A) do { \
    if (dOwn <= (A)) { \
        btx = bxv + (S) * sxv;  bty = byv + (S) * syv;  btz = bzv + (S) * szv; \
        ex = mx; ey = my; ez = mz; \
        WRE(0); \
    } \
    PSYNC(); \
    if (dOwn <= (A) - 1) { \
        STAGE(0);                          /* k1 */ \
        ax = kx; ay = ky; az = kz; \
        ex = mx + hh * kx; ey = my + hh * ky; ez = mz + hh * kz; \
        WRE(1); \
    } \
    PSYNC(); \
    if (dOwn <= (A) - 2) { \
        STAGE(1);                          /* k2 */ \
        ax += 2.0f * kx; ay += 2.0f * ky; az += 2.0f * kz; \
        ex = mx + hh * kx; ey = my + hh * ky; ez = mz + hh * kz; \
        WRE(0); \
    } \
    PSYNC(); \
    if (dOwn <= (A) - 3) { \
        STAGE(0);                          /* k3 */ \
        ax += 2.0f * kx; ay += 2.0f * ky; az += 2.0f * kz; \
        ex = mx + h * kx; ey = my + h * ky; ez = mz + h * kz; \
        WRE(1); \
    } \
    PSYNC(); \
    if (dOwn <= (A) - 4) { \
        STAGE(1);                          /* k4 */ \
        ax += kx; ay += ky; az += kz; \
        mx += h6 * ax; my += h6 * ay; mz += h6 * az; \
    } \
} while (0)

#define PROBE(I_) do { \
    if (waveP) { \
        float c = pcell ? mx * ms * pm : 0.0f; \
        _Pragma("unroll") \
        for (int off = 32; off > 0; off >>= 1) c += __shfl_down(c, off, 64); \
        if (lane0) atomicAdd(&priv[b * TST + (I_)], c); \
    } \
} while (0)

    for (int i = 0; i < TST; i += 2) {
        const int I = i >> 1;                 // 2-step group index

        // Halo refresh ONCE per group: poll my cell's stamped slot (parity
        // I&1) until stamp>=I. Skipped at I==0 (m_0 analytic) and for cells
        // with dOwn>8 (never participate). Miss -> s_sleep(1) backoff.
        // Cross-block chain strictly decreases group index -> no premature
        // overwrite, no deadlock (proof as R5-R7).
        if (haloT && I) {
            const v4f* p = pub + (I & 1) * pubStride + slotOff;
            for (;;) {
                v4f hv = ld16_dev(p);
                if (__float_as_int(hv.w) >= I) { mx = hv.x; my = hv.y; mz = hv.z; break; }
                __builtin_amdgcn_s_sleep(1);
            }
        }

        RK4_STEP(sigS[i],     8);             // step A -> m_{i+1} (d<=4 cells)
        PROBE(i);
        RK4_STEP(sigS[i + 1], 4);             // step B -> m_{i+2} (own cells)
        PROBE(i + 1);

        // publish m_{i+2}, stamp I+1, parity (I+1)&1 (fire-and-forget, global)
        if (own) st16_dev(pub + ((I + 1) & 1) * pubStride + slotOff,
                          (v4f){mx, my, mz, __int_as_float(I + 1)});
    }

    // ---- finalize ----
    __syncthreads();   // TRUE barrier: drains vmcnt -> publishes/atomics done
    if (t == 0) agstorei(&doneA[b], 0x5D0000 | hasPr);

    if (b == 0) {
        if (t < NB) {
            int v;
            for (;;) { v = agloadi(&doneA[t]); if ((v & ~1) == 0x5D0000) break;
                       __builtin_amdgcn_s_sleep(8); }
            pfl[t] = v & 1;
        }
        __syncthreads();
        float ps = 0.0f;
        for (int k = t; k < 65536; k += NT) ps += probe_mask[k];
        #pragma unroll
        for (int off = 32; off > 0; off >>= 1) ps += __shfl_down(ps, off, 64);
        if (lane0) redS[wv] = ps;
        __syncthreads();
        if (t == 0) { float q = 0.0f; for (int w = 0; w < NW; ++w) q += redS[w]; pmsS = q; }
        __syncthreads();
        const float pms = pmsS;
        for (int o = t; o < TST; o += NT) {
            float sm = 0.0f;
            for (int j = 0; j < NB; ++j) if (pfl[j]) sm += agload(&priv[j * TST + o]);
            out[o] = sm / pms;
        }
    }
}

extern "C" void kernel_launch(void* const* d_in, const int* in_sizes, int n_in,
                              void* d_out, int out_size, void* d_ws, size_t ws_size,
                              hipStream_t stream)
{
    const float* signal = (const float*)d_in[0];
    const float* B_ext  = (const float*)d_in[1];
    const float* Msat   = (const float*)d_in[2];
    const float* src    = (const float*)d_in[3];
    const float* probe  = (const float*)d_in[4];
    float* out = (float*)d_out;
    float* ws  = (float*)d_ws;

    void* args[] = { &signal, &B_ext, &Msat, &src, &probe, &out, &ws };
    (void)in_sizes; (void)n_in; (void)out_size; (void)ws_size;

    // CHAMPION (R11, 2642us): 256 blocks (16x16 own tiles, 8-deep halo) x
    // 1024 threads, 1 cell/thread + cone predication (participate in phase p
    // iff L1-distance d <= 8-p). Phase sync = one hw s_barrier per stage;
    // cross-block exchange every 2 RK4 steps via stamped IF$ slots. 15 rounds
    // of counter-diagnosed variants (sync mechanism, DS-traffic cuts,
    // occupancy, coarsening) all land 2642-3300 -> this structure's
    // latency/sync floor (~1540 cy/stage-phase, no pipe saturated).
    hipLaunchCooperativeKernel(reinterpret_cast<void*>(mm_solver),
                               dim3(NB), dim3(NT), args, 0, stream);
}